// Round 4
// baseline (692.991 us; speedup 1.0000x reference)
//
#include <hip/hip_runtime.h>
#include <math.h>

typedef __attribute__((ext_vector_type(8))) short bf16x8;
typedef __attribute__((ext_vector_type(4))) float f32x4;

// round-to-nearest-even float -> bf16 (as short)
__device__ __forceinline__ short f2bf(float f) {
    unsigned u = __float_as_uint(f);
    unsigned r = (u + 0x7FFFu + ((u >> 16) & 1u)) >> 16;
    return (short)r;
}

// XOR swizzle of a byte offset within a row (spreads 16B slots across 8 bank-groups)
__device__ __forceinline__ int swz(int row, int kbyte) {
    return kbyte ^ ((row & 7) << 4);
}

// ---------- sort pass A: histogram of tgt ----------
__global__ __launch_bounds__(256) void hist_kernel(
    const int* __restrict__ eidx, int* __restrict__ cnt, int E)
{
    for (long e = (long)blockIdx.x * blockDim.x + threadIdx.x; e < E;
         e += (long)gridDim.x * blockDim.x)
        atomicAdd(&cnt[eidx[E + e]], 1);
}

// ---------- sort pass B: exclusive scan (single block) -> cursor ----------
__global__ __launch_bounds__(1024) void scan_kernel(
    const int* __restrict__ cnt, int* __restrict__ cursor, int N)
{
    __shared__ int pa[1024], pb[1024];
    int t = threadIdx.x;
    int chunk = (N + 1023) >> 10;
    int lo = t * chunk, hi = min(lo + chunk, N);
    int s = 0;
    for (int j = lo; j < hi; j++) s += cnt[j];
    pa[t] = s;
    __syncthreads();
    int* src = pa; int* dst = pb;
    for (int off = 1; off < 1024; off <<= 1) {
        int val = src[t];
        if (t >= off) val += src[t - off];
        dst[t] = val;
        __syncthreads();
        int* tmp = src; src = dst; dst = tmp;
    }
    int excl = (t == 0) ? 0 : src[t - 1];
    for (int j = lo; j < hi; j++) { cursor[j] = excl; excl += cnt[j]; }
}

// ---------- sort pass C: scatter edge ids into tgt-sorted order ----------
__global__ __launch_bounds__(256) void scatter_kernel(
    const int* __restrict__ eidx, int* __restrict__ cursor,
    int* __restrict__ sorted, int E)
{
    for (long e = (long)blockIdx.x * blockDim.x + threadIdx.x; e < E;
         e += (long)gridDim.x * blockDim.x) {
        int tg = eidx[E + e];
        int pos = atomicAdd(&cursor[tg], 1);
        sorted[pos] = (int)e;
    }
}

// ---------- K1: q,k,v = node_features @ {Wq,Wk,Wv} ----------
__global__ __launch_bounds__(256) void qkv_kernel(
    const float* __restrict__ x,
    const float* __restrict__ Wq, const float* __restrict__ Wk, const float* __restrict__ Wv,
    float* __restrict__ q, float* __restrict__ k, float* __restrict__ v, int N)
{
    __shared__ float sW[3][64][64];
    __shared__ float sx[4][64];
    int t = threadIdx.x;
    for (int i = t; i < 4096; i += 256) {
        sW[0][i >> 6][i & 63] = Wq[i];
        sW[1][i >> 6][i & 63] = Wk[i];
        sW[2][i >> 6][i & 63] = Wv[i];
    }
    __syncthreads();
    int c = t & 63, sub = t >> 6;
    for (int base = blockIdx.x * 4; base < N; base += gridDim.x * 4) {
        int n = base + sub;
        if (n < N) sx[sub][c] = x[(size_t)n * 64 + c];
        __syncthreads();
        if (n < N) {
            float aq = 0.f, ak = 0.f, av = 0.f;
            #pragma unroll
            for (int i = 0; i < 64; i++) {
                float xv = sx[sub][i];
                aq += xv * sW[0][i][c];
                ak += xv * sW[1][i][c];
                av += xv * sW[2][i][c];
            }
            q[(size_t)n * 64 + c] = aq;
            k[(size_t)n * 64 + c] = ak;
            v[(size_t)n * 64 + c] = av;
        }
        __syncthreads();
    }
}

// ---- stage 64x64 weight (transposed, bf16, swizzled rows of 128B) ----
__device__ __forceinline__ void stage_w64T(const float* __restrict__ W, short* sWT, int t) {
    for (int i = t; i < 4096; i += 256) {
        int k = i >> 6, n = i & 63;             // W[k][n], coalesced in n
        short vv = f2bf(W[i]);
        int kb = k * 2;
        int off = n * 128 + (swz(n, kb & ~15) | (kb & 15));
        *(short*)((char*)sWT + off) = vv;
    }
}

// ---------- K2: fused edge pass over TGT-SORTED edges ----------
// ep via MFMA, score+exp, run-compressed atomic aggregation
__global__ __launch_bounds__(256) void edge_kernel(
    const float* __restrict__ ef, const int* __restrict__ eidx,
    const int* __restrict__ sorted,
    const float* __restrict__ q, const float* __restrict__ k,
    const float* __restrict__ v, const float* __restrict__ We,
    float* __restrict__ denom, float* __restrict__ agg, int E)
{
    __shared__ short sWeT[4096];
    __shared__ float ep_lds[64 * 66];
    __shared__ float ex_lds[64 * 4];
    __shared__ int sedge[64], sidx[64], tidx[64];
    int t = threadIdx.x;
    stage_w64T(We, sWeT, t);
    __syncthreads();

    int lane = t & 63, w = t >> 6;
    int ntiles = E >> 6;
    for (int tile = blockIdx.x; tile < ntiles; tile += gridDim.x) {
        size_t tile64 = (size_t)tile * 64;
        if (t < 64) {
            int se = sorted[tile64 + t];
            sedge[t] = se;
            sidx[t] = eidx[se];
            tidx[t] = eidx[E + se];
        }
        __syncthreads();

        // --- phase A: ep = ef[sorted rows] @ We via MFMA ---
        {
            f32x4 acc[4];
            #pragma unroll
            for (int nt = 0; nt < 4; nt++) acc[nt] = (f32x4){0.f, 0.f, 0.f, 0.f};
            int erow = sedge[w * 16 + (lane & 15)];
            #pragma unroll
            for (int kk = 0; kk < 2; kk++) {
                const float* base = ef + (size_t)erow * 64 + kk * 32 + (lane >> 4) * 8;
                float4 x0 = *(const float4*)(base);
                float4 x1 = *(const float4*)(base + 4);
                bf16x8 a;
                a[0] = f2bf(x0.x); a[1] = f2bf(x0.y); a[2] = f2bf(x0.z); a[3] = f2bf(x0.w);
                a[4] = f2bf(x1.x); a[5] = f2bf(x1.y); a[6] = f2bf(x1.z); a[7] = f2bf(x1.w);
                #pragma unroll
                for (int nt = 0; nt < 4; nt++) {
                    int n = nt * 16 + (lane & 15);
                    int kb = kk * 64 + (lane >> 4) * 16;
                    bf16x8 b = *(const bf16x8*)((const char*)sWeT + n * 128 + swz(n, kb));
                    acc[nt] = __builtin_amdgcn_mfma_f32_16x16x32_bf16(a, b, acc[nt], 0, 0, 0);
                }
            }
            #pragma unroll
            for (int nt = 0; nt < 4; nt++)
                #pragma unroll
                for (int r = 0; r < 4; r++) {
                    int row = w * 16 + (lane >> 4) * 4 + r;
                    int col = nt * 16 + (lane & 15);
                    ep_lds[row * 66 + col] = acc[nt][r];
                }
        }
        __syncthreads();

        // --- phase B: scores + exp (thread = edge t>>2, head t&3) ---
        {
            int e_loc = t >> 2, h = t & 3;
            int src = sidx[e_loc], tgt = tidx[e_loc];
            const float4* qp = (const float4*)(q + (size_t)tgt * 64 + h * 16);
            const float4* kp = (const float4*)(k + (size_t)src * 64 + h * 16);
            const float* epp = ep_lds + e_loc * 66 + h * 16;
            float s = 0.f;
            #pragma unroll
            for (int j = 0; j < 4; j++) {
                float4 qq = qp[j];
                float4 kk = kp[j];
                s += qq.x * (kk.x + epp[j * 4 + 0]);
                s += qq.y * (kk.y + epp[j * 4 + 1]);
                s += qq.z * (kk.z + epp[j * 4 + 2]);
                s += qq.w * (kk.w + epp[j * 4 + 3]);
            }
            ex_lds[e_loc * 4 + h] = __expf(s * 0.25f);
        }
        __syncthreads();

        // --- phase C: run-compressed aggregation (edges sorted by tgt) ---
        {
            int h = lane >> 4;
            float vv[16];
            #pragma unroll
            for (int i = 0; i < 16; i++)
                vv[i] = v[(size_t)sidx[w * 16 + i] * 64 + lane];
            int cur = tidx[w * 16];
            float acc = 0.f, den = 0.f;
            #pragma unroll
            for (int i = 0; i < 16; i++) {
                int e_loc = w * 16 + i;
                int tg = tidx[e_loc];
                if (tg != cur) {                    // wave-uniform branch
                    atomicAdd(&agg[(size_t)cur * 64 + lane], acc);
                    if ((lane & 15) == 0) atomicAdd(&denom[(size_t)cur * 4 + h], den);
                    acc = 0.f; den = 0.f; cur = tg;
                }
                float ex = ex_lds[e_loc * 4 + h];
                acc += ex * (vv[i] + ep_lds[e_loc * 66 + lane]);
                den += ex;
            }
            atomicAdd(&agg[(size_t)cur * 64 + lane], acc);
            if ((lane & 15) == 0) atomicAdd(&denom[(size_t)cur * 4 + h], den);
        }
        __syncthreads();
    }
}

// ---------- K3: new_nodes = node_features + (agg/denom) @ Wo -> bf16 ----------
__global__ __launch_bounds__(256) void wo_kernel(
    const float* __restrict__ agg, const float* __restrict__ denom,
    const float* __restrict__ x,
    const float* __restrict__ Wo, short* __restrict__ out_bf, int N)
{
    __shared__ float sW[64][64];
    __shared__ float sx[4][64];
    int t = threadIdx.x;
    for (int i = t; i < 4096; i += 256) sW[i >> 6][i & 63] = Wo[i];
    __syncthreads();
    int c = t & 63, sub = t >> 6;
    for (int base = blockIdx.x * 4; base < N; base += gridDim.x * 4) {
        int n = base + sub;
        if (n < N) {
            float d = denom[(size_t)n * 4 + (c >> 4)] + 1e-9f;
            sx[sub][c] = agg[(size_t)n * 64 + c] / d;
        }
        __syncthreads();
        if (n < N) {
            float acc = 0.f;
            #pragma unroll
            for (int i = 0; i < 64; i++) acc += sx[sub][i] * sW[i][c];
            out_bf[(size_t)n * 64 + c] = f2bf(x[(size_t)n * 64 + c] + acc);
        }
        __syncthreads();
    }
}

// ---------- K4: classifier via MFMA; nn already bf16; 2nd layer in registers ----------
__global__ __launch_bounds__(256, 4) void cls_kernel(
    const short* __restrict__ nnb, const float* __restrict__ ef,
    const int* __restrict__ eidx,
    const float* __restrict__ W1, const float* __restrict__ b1,
    const float* __restrict__ W2, const float* __restrict__ b2,
    float* __restrict__ out, int E)
{
    __shared__ short sWt1[64 * 192];        // [n][k] bf16, swizzled (384B rows)
    __shared__ float sW2[128];
    __shared__ float sb1[64];
    __shared__ float sb2[2];
    __shared__ int sidx[64], tidx[64];
    int t = threadIdx.x;
    for (int i = t; i < 192 * 64; i += 256) {
        int k = i >> 6, n = i & 63;          // W1[k][n], coalesced in n
        short vv = f2bf(W1[i]);
        int kb = k * 2;
        int off = n * 384 + (swz(n, kb & ~15) | (kb & 15));
        *(short*)((char*)sWt1 + off) = vv;
    }
    if (t < 128) sW2[t] = W2[t];
    if (t < 64) sb1[t] = b1[t];
    if (t < 2) sb2[t] = b2[t];
    __syncthreads();

    int lane = t & 63, w = t >> 6;
    int ntiles = E >> 6;
    for (int tile = blockIdx.x; tile < ntiles; tile += gridDim.x) {
        size_t tile64 = (size_t)tile * 64;
        if (t < 64) {
            sidx[t] = eidx[tile64 + t];
            tidx[t] = eidx[(size_t)E + tile64 + t];
        }
        __syncthreads();

        f32x4 acc[4];
        #pragma unroll
        for (int nt = 0; nt < 4; nt++) acc[nt] = (f32x4){0.f, 0.f, 0.f, 0.f};

        int e16 = w * 16 + (lane & 15);      // this lane's edge row within the tile
        #pragma unroll
        for (int kk = 0; kk < 6; kk++) {
            bf16x8 a;
            if (kk < 4) {
                int nd = (kk < 2) ? sidx[e16] : tidx[e16];
                a = *(const bf16x8*)(nnb + (size_t)nd * 64 + (kk & 1) * 32 + (lane >> 4) * 8);
            } else {
                const float* base = ef + (tile64 + (size_t)e16) * 64 + (kk - 4) * 32;
                const float4* p = (const float4*)(base + (lane >> 4) * 8);
                float4 x0 = p[0], x1 = p[1];
                a[0] = f2bf(x0.x); a[1] = f2bf(x0.y); a[2] = f2bf(x0.z); a[3] = f2bf(x0.w);
                a[4] = f2bf(x1.x); a[5] = f2bf(x1.y); a[6] = f2bf(x1.z); a[7] = f2bf(x1.w);
            }
            #pragma unroll
            for (int nt = 0; nt < 4; nt++) {
                int n = nt * 16 + (lane & 15);
                int kb = kk * 64 + (lane >> 4) * 16;
                bf16x8 b = *(const bf16x8*)((const char*)sWt1 + n * 384 + swz(n, kb));
                acc[nt] = __builtin_amdgcn_mfma_f32_16x16x32_bf16(a, b, acc[nt], 0, 0, 0);
            }
        }

        // bias + exact GELU + second layer [64,64]@[64,2] via in-register shfl reduce.
        #pragma unroll
        for (int r = 0; r < 4; r++) {
            float p0 = 0.f, p1 = 0.f;
            #pragma unroll
            for (int nt = 0; nt < 4; nt++) {
                int col = nt * 16 + (lane & 15);
                float h = acc[nt][r] + sb1[col];
                float g = 0.5f * h * (1.f + erff(h * 0.70710678118654752f));
                p0 += g * sW2[col * 2 + 0];
                p1 += g * sW2[col * 2 + 1];
            }
            #pragma unroll
            for (int o = 1; o < 16; o <<= 1) {
                p0 += __shfl_xor(p0, o, 64);
                p1 += __shfl_xor(p1, o, 64);
            }
            if ((lane & 15) == 0) {
                int row = w * 16 + (lane >> 4) * 4 + r;
                out[(tile64 + (size_t)row) * 2 + 0] = p0 + sb2[0];
                out[(tile64 + (size_t)row) * 2 + 1] = p1 + sb2[1];
            }
        }
        __syncthreads();
    }
}

extern "C" void kernel_launch(void* const* d_in, const int* in_sizes, int n_in,
                              void* d_out, int out_size, void* d_ws, size_t ws_size,
                              hipStream_t stream)
{
    const float* node = (const float*)d_in[0];
    const float* ef   = (const float*)d_in[1];
    const int*   eidx = (const int*)d_in[2];
    const float* Wq   = (const float*)d_in[3];
    const float* Wk   = (const float*)d_in[4];
    const float* Wv   = (const float*)d_in[5];
    const float* We   = (const float*)d_in[6];
    const float* Wo   = (const float*)d_in[7];
    const float* W1   = (const float*)d_in[8];
    const float* b1   = (const float*)d_in[9];
    const float* W2   = (const float*)d_in[10];
    const float* b2   = (const float*)d_in[11];
    float* out = (float*)d_out;

    int N = in_sizes[0] / 64;
    int E = in_sizes[1] / 64;
    size_t N64 = (size_t)N * 64;

    float* q      = (float*)d_ws;
    float* k      = q + N64;
    float* v      = k + N64;
    float* agg    = v + N64;                    // N*64 unnormalized, zeroed
    float* denom  = agg + N64;                  // N*4, zeroed
    int*   cnt    = (int*)(denom + (size_t)N * 4);  // N, zeroed
    int*   cursor = cnt + N;                    // N (written by scan)
    int*   sorted = cursor + N;                 // E
    short* newnb  = (short*)(sorted + E);       // N*64 bf16

    // zero agg + denom + cnt in one contiguous memset
    hipMemsetAsync(agg, 0, (N64 + (size_t)N * 4 + (size_t)N) * 4, stream);

    hist_kernel<<<2048, 256, 0, stream>>>(eidx, cnt, E);
    scan_kernel<<<1, 1024, 0, stream>>>(cnt, cursor, N);
    scatter_kernel<<<2048, 256, 0, stream>>>(eidx, cursor, sorted, E);
    qkv_kernel<<<512, 256, 0, stream>>>(node, Wq, Wk, Wv, q, k, v, N);
    edge_kernel<<<2048, 256, 0, stream>>>(ef, eidx, sorted, q, k, v, We, denom, agg, E);
    wo_kernel<<<512, 256, 0, stream>>>(agg, denom, node, Wo, newnb, N);
    cls_kernel<<<2048, 256, 0, stream>>>(newnb, ef, eidx, W1, b1, W2, b2, out, E);
}

// Round 8
// 560.159 us; speedup vs baseline: 1.2371x; 1.2371x over previous
//
#include <hip/hip_runtime.h>
#include <math.h>

typedef __attribute__((ext_vector_type(8))) short bf16x8;
typedef __attribute__((ext_vector_type(4))) float f32x4;

// round-to-nearest-even float -> bf16 (as short)
__device__ __forceinline__ short f2bf(float f) {
    unsigned u = __float_as_uint(f);
    unsigned r = (u + 0x7FFFu + ((u >> 16) & 1u)) >> 16;
    return (short)r;
}
__device__ __forceinline__ float bf2f(short s) {
    return __uint_as_float(((unsigned)(unsigned short)s) << 16);
}

// XOR swizzle of a byte offset within a row (spreads 16B slots across 8 bank-groups)
__device__ __forceinline__ int swz(int row, int kbyte) {
    return kbyte ^ ((row & 7) << 4);
}

// ---------- sort A: histogram of tgt ----------
__global__ __launch_bounds__(256) void hist_kernel(
    const int* __restrict__ eidx, int* __restrict__ cnt, int E)
{
    for (long e = (long)blockIdx.x * blockDim.x + threadIdx.x; e < E;
         e += (long)gridDim.x * blockDim.x)
        atomicAdd(&cnt[eidx[E + e]], 1);
}

// ---------- sort B1: per-block inclusive scan + block sums ----------
__global__ __launch_bounds__(256) void scanA_kernel(
    const int* __restrict__ cnt, int* __restrict__ tmp, int* __restrict__ bsum, int N)
{
    __shared__ int sa[256], sb_[256];
    int t = threadIdx.x;
    int i = blockIdx.x * 256 + t;
    int val = (i < N) ? cnt[i] : 0;
    sa[t] = val;
    __syncthreads();
    int* src = sa; int* dst = sb_;
    for (int off = 1; off < 256; off <<= 1) {
        int v2 = src[t];
        if (t >= off) v2 += src[t - off];
        dst[t] = v2;
        __syncthreads();
        int* tm = src; src = dst; dst = tm;
    }
    if (i < N) tmp[i] = src[t];
    if (t == 255) bsum[blockIdx.x] = src[255];
}

// ---------- sort B2: exclusive scan of block sums (1 small block) ----------
__global__ __launch_bounds__(256) void scanB_kernel(
    const int* __restrict__ bsum, int* __restrict__ boff, int NB)
{
    __shared__ int sa[256], sb_[256];
    int t = threadIdx.x;
    int val = (t < NB) ? bsum[t] : 0;
    sa[t] = val;
    __syncthreads();
    int* src = sa; int* dst = sb_;
    for (int off = 1; off < 256; off <<= 1) {
        int v2 = src[t];
        if (t >= off) v2 += src[t - off];
        dst[t] = v2;
        __syncthreads();
        int* tm = src; src = dst; dst = tm;
    }
    if (t < NB) boff[t] = src[t] - val;   // exclusive
}

// ---------- sort B3: cursor = global exclusive prefix ----------
__global__ __launch_bounds__(256) void scanC_kernel(
    const int* __restrict__ cnt, const int* __restrict__ tmp,
    const int* __restrict__ boff, int* __restrict__ cursor, int N)
{
    int i = blockIdx.x * 256 + threadIdx.x;
    if (i < N) cursor[i] = tmp[i] - cnt[i] + boff[blockIdx.x];
}

// ---------- sort C: scatter packed (edge,src,tgt) records in tgt-sorted order ----------
__global__ __launch_bounds__(256) void scatter_kernel(
    const int* __restrict__ eidx, int* __restrict__ cursor,
    int4* __restrict__ sortedq, int E)
{
    for (long e = (long)blockIdx.x * blockDim.x + threadIdx.x; e < E;
         e += (long)gridDim.x * blockDim.x) {
        int sr = eidx[e];
        int tg = eidx[E + e];
        int pos = atomicAdd(&cursor[tg], 1);
        sortedq[pos] = make_int4((int)e, sr, tg, 0);
    }
}

// ---------- K1: q|k|v = node @ [Wq|Wk|Wv] via MFMA -> bf16 ----------
__global__ __launch_bounds__(256) void qkv_kernel(
    const float* __restrict__ x,
    const float* __restrict__ Wq, const float* __restrict__ Wk, const float* __restrict__ Wv,
    short* __restrict__ qb, short* __restrict__ kb_, short* __restrict__ vb, int N)
{
    __shared__ short sWT[12288];   // 192 n-rows x 64 k, bf16, 128B rows, swizzled
    int t = threadIdx.x;
    for (int i = t; i < 4096; i += 256) {
        int k = i >> 6, n = i & 63;
        int kby = k * 2;
        int off = n * 128 + (swz(n, kby & ~15) | (kby & 15));
        *(short*)((char*)sWT + off) = f2bf(Wq[i]);
        *(short*)((char*)sWT + 8192 + off) = f2bf(Wk[i]);
        *(short*)((char*)sWT + 16384 + off) = f2bf(Wv[i]);
    }
    __syncthreads();

    int lane = t & 63, w = t >> 6;
    int tile = blockIdx.x;
    f32x4 acc[12];
    #pragma unroll
    for (int nt = 0; nt < 12; nt++) acc[nt] = (f32x4){0.f, 0.f, 0.f, 0.f};

    int gr = tile * 64 + w * 16 + (lane & 15);
    int grc = min(gr, N - 1);
    #pragma unroll
    for (int kk = 0; kk < 2; kk++) {
        const float* base = x + (size_t)grc * 64 + kk * 32 + (lane >> 4) * 8;
        float4 x0 = *(const float4*)(base);
        float4 x1 = *(const float4*)(base + 4);
        bf16x8 a;
        a[0] = f2bf(x0.x); a[1] = f2bf(x0.y); a[2] = f2bf(x0.z); a[3] = f2bf(x0.w);
        a[4] = f2bf(x1.x); a[5] = f2bf(x1.y); a[6] = f2bf(x1.z); a[7] = f2bf(x1.w);
        #pragma unroll
        for (int nt = 0; nt < 12; nt++) {
            int ng = nt * 16 + (lane & 15);
            int kby = kk * 64 + (lane >> 4) * 16;
            bf16x8 b = *(const bf16x8*)((const char*)sWT + ng * 128 + swz(ng, kby));
            acc[nt] = __builtin_amdgcn_mfma_f32_16x16x32_bf16(a, b, acc[nt], 0, 0, 0);
        }
    }
    #pragma unroll
    for (int nt = 0; nt < 12; nt++)
        #pragma unroll
        for (int r = 0; r < 4; r++) {
            int row = tile * 64 + w * 16 + (lane >> 4) * 4 + r;
            if (row < N) {
                int col = nt * 16 + (lane & 15);
                short vv = f2bf(acc[nt][r]);
                if (col < 64)       qb[(size_t)row * 64 + col] = vv;
                else if (col < 128) kb_[(size_t)row * 64 + col - 64] = vv;
                else                vb[(size_t)row * 64 + col - 128] = vv;
            }
        }
}

// ---- stage 64x64 weight (transposed, bf16, swizzled rows of 128B) ----
__device__ __forceinline__ void stage_w64T(const float* __restrict__ W, short* sWT, int t) {
    for (int i = t; i < 4096; i += 256) {
        int k = i >> 6, n = i & 63;
        short vv = f2bf(W[i]);
        int kby = k * 2;
        int off = n * 128 + (swz(n, kby & ~15) | (kby & 15));
        *(short*)((char*)sWT + off) = vv;
    }
}

// ---------- K2: fused edge pass over tgt-sorted records ----------
__global__ __launch_bounds__(256) void edge_kernel(
    const float* __restrict__ ef, const int4* __restrict__ sortedq,
    const short* __restrict__ qb, const short* __restrict__ kb_,
    const short* __restrict__ vb, const float* __restrict__ We,
    float* __restrict__ denom, float* __restrict__ agg, int E)
{
    __shared__ short sWeT[4096];
    __shared__ float ep_lds[64 * 66];
    __shared__ float ex_lds[64 * 4];
    __shared__ int sedge[64], sidx[64], tidx[64];
    int t = threadIdx.x;
    stage_w64T(We, sWeT, t);
    __syncthreads();

    int lane = t & 63, w = t >> 6;
    int ntiles = E >> 6;
    for (int tile = blockIdx.x; tile < ntiles; tile += gridDim.x) {
        size_t tile64 = (size_t)tile * 64;
        if (t < 64) {
            int4 rec = sortedq[tile64 + t];
            sedge[t] = rec.x;
            sidx[t] = rec.y;
            tidx[t] = rec.z;
        }
        __syncthreads();

        // --- phase A: ep = ef[sorted rows] @ We via MFMA (nontemporal ef) ---
        {
            f32x4 acc[4];
            #pragma unroll
            for (int nt = 0; nt < 4; nt++) acc[nt] = (f32x4){0.f, 0.f, 0.f, 0.f};
            int erow = sedge[w * 16 + (lane & 15)];
            #pragma unroll
            for (int kk = 0; kk < 2; kk++) {
                const f32x4* base = (const f32x4*)(ef + (size_t)erow * 64 + kk * 32 + (lane >> 4) * 8);
                f32x4 x0 = __builtin_nontemporal_load(base);
                f32x4 x1 = __builtin_nontemporal_load(base + 1);
                bf16x8 a;
                a[0] = f2bf(x0.x); a[1] = f2bf(x0.y); a[2] = f2bf(x0.z); a[3] = f2bf(x0.w);
                a[4] = f2bf(x1.x); a[5] = f2bf(x1.y); a[6] = f2bf(x1.z); a[7] = f2bf(x1.w);
                #pragma unroll
                for (int nt = 0; nt < 4; nt++) {
                    int n = nt * 16 + (lane & 15);
                    int kby = kk * 64 + (lane >> 4) * 16;
                    bf16x8 b = *(const bf16x8*)((const char*)sWeT + n * 128 + swz(n, kby));
                    acc[nt] = __builtin_amdgcn_mfma_f32_16x16x32_bf16(a, b, acc[nt], 0, 0, 0);
                }
            }
            #pragma unroll
            for (int nt = 0; nt < 4; nt++)
                #pragma unroll
                for (int r = 0; r < 4; r++) {
                    int row = w * 16 + (lane >> 4) * 4 + r;
                    int col = nt * 16 + (lane & 15);
                    ep_lds[row * 66 + col] = acc[nt][r];
                }
        }
        __syncthreads();

        // --- phase B: scores + exp (thread = edge t>>2, head t&3); bf16 q,k ---
        {
            int e_loc = t >> 2, h = t & 3;
            int src = sidx[e_loc], tgt = tidx[e_loc];
            const bf16x8* qp = (const bf16x8*)(qb + (size_t)tgt * 64 + h * 16);
            const bf16x8* kp = (const bf16x8*)(kb_ + (size_t)src * 64 + h * 16);
            bf16x8 q0 = qp[0], q1 = qp[1];
            bf16x8 k0 = kp[0], k1 = kp[1];
            const float* epp = ep_lds + e_loc * 66 + h * 16;
            float s = 0.f;
            #pragma unroll
            for (int j = 0; j < 8; j++) s += bf2f(q0[j]) * (bf2f(k0[j]) + epp[j]);
            #pragma unroll
            for (int j = 0; j < 8; j++) s += bf2f(q1[j]) * (bf2f(k1[j]) + epp[8 + j]);
            ex_lds[e_loc * 4 + h] = __expf(s * 0.25f);
        }
        __syncthreads();

        // --- phase C: run-compressed aggregation (edges sorted by tgt) ---
        {
            int h = lane >> 4;
            float vv[16];
            #pragma unroll
            for (int i = 0; i < 16; i++)
                vv[i] = bf2f(vb[(size_t)sidx[w * 16 + i] * 64 + lane]);
            int cur = tidx[w * 16];
            float acc = 0.f, den = 0.f;
            #pragma unroll
            for (int i = 0; i < 16; i++) {
                int e_loc = w * 16 + i;
                int tg = tidx[e_loc];
                if (tg != cur) {                    // wave-uniform branch
                    atomicAdd(&agg[(size_t)cur * 64 + lane], acc);
                    if ((lane & 15) == 0) atomicAdd(&denom[(size_t)cur * 4 + h], den);
                    acc = 0.f; den = 0.f; cur = tg;
                }
                float ex = ex_lds[e_loc * 4 + h];
                acc += ex * (vv[i] + ep_lds[e_loc * 66 + lane]);
                den += ex;
            }
            atomicAdd(&agg[(size_t)cur * 64 + lane], acc);
            if ((lane & 15) == 0) atomicAdd(&denom[(size_t)cur * 4 + h], den);
        }
        __syncthreads();
    }
}

// ---------- K3: new_nodes = x + (agg/denom) @ Wo via MFMA -> bf16 ----------
__global__ __launch_bounds__(256) void wo_kernel(
    const float* __restrict__ agg, const float* __restrict__ denom,
    const float* __restrict__ x,
    const float* __restrict__ Wo, short* __restrict__ nnb, int N)
{
    __shared__ short sWT[4096];
    int t = threadIdx.x;
    stage_w64T(Wo, sWT, t);
    __syncthreads();

    int lane = t & 63, w = t >> 6;
    int tile = blockIdx.x;
    f32x4 acc[4];
    #pragma unroll
    for (int nt = 0; nt < 4; nt++) acc[nt] = (f32x4){0.f, 0.f, 0.f, 0.f};

    int gr = tile * 64 + w * 16 + (lane & 15);
    int grc = min(gr, N - 1);
    #pragma unroll
    for (int kk = 0; kk < 2; kk++) {
        int fbase = kk * 32 + (lane >> 4) * 8;
        int h = fbase >> 4;                 // all 8 elems share one head
        float d = denom[(size_t)grc * 4 + h] + 1e-9f;
        const float* base = agg + (size_t)grc * 64 + fbase;
        float4 x0 = *(const float4*)(base);
        float4 x1 = *(const float4*)(base + 4);
        float inv = 1.f / d;
        bf16x8 a;
        a[0] = f2bf(x0.x * inv); a[1] = f2bf(x0.y * inv);
        a[2] = f2bf(x0.z * inv); a[3] = f2bf(x0.w * inv);
        a[4] = f2bf(x1.x * inv); a[5] = f2bf(x1.y * inv);
        a[6] = f2bf(x1.z * inv); a[7] = f2bf(x1.w * inv);
        #pragma unroll
        for (int nt = 0; nt < 4; nt++) {
            int n = nt * 16 + (lane & 15);
            int kby = kk * 64 + (lane >> 4) * 16;
            bf16x8 b = *(const bf16x8*)((const char*)sWT + n * 128 + swz(n, kby));
            acc[nt] = __builtin_amdgcn_mfma_f32_16x16x32_bf16(a, b, acc[nt], 0, 0, 0);
        }
    }
    #pragma unroll
    for (int nt = 0; nt < 4; nt++)
        #pragma unroll
        for (int r = 0; r < 4; r++) {
            int row = tile * 64 + w * 16 + (lane >> 4) * 4 + r;
            if (row < N) {
                int col = nt * 16 + (lane & 15);
                nnb[(size_t)row * 64 + col] = f2bf(x[(size_t)row * 64 + col] + acc[nt][r]);
            }
        }
}

// ---------- K4: classifier via MFMA; nn bf16; 2nd layer in registers ----------
__global__ __launch_bounds__(256, 4) void cls_kernel(
    const short* __restrict__ nnb, const float* __restrict__ ef,
    const int* __restrict__ eidx,
    const float* __restrict__ W1, const float* __restrict__ b1,
    const float* __restrict__ W2, const float* __restrict__ b2,
    float* __restrict__ out, int E)
{
    __shared__ short sWt1[64 * 192];        // [n][k] bf16, swizzled (384B rows)
    __shared__ float sW2[128];
    __shared__ float sb1[64];
    __shared__ float sb2[2];
    __shared__ int sidx[64], tidx[64];
    int t = threadIdx.x;
    for (int i = t; i < 192 * 64; i += 256) {
        int k = i >> 6, n = i & 63;
        short vv = f2bf(W1[i]);
        int kby = k * 2;
        int off = n * 384 + (swz(n, kby & ~15) | (kby & 15));
        *(short*)((char*)sWt1 + off) = vv;
    }
    if (t < 128) sW2[t] = W2[t];
    if (t < 64) sb1[t] = b1[t];
    if (t < 2) sb2[t] = b2[t];
    __syncthreads();

    int lane = t & 63, w = t >> 6;
    int ntiles = E >> 6;
    for (int tile = blockIdx.x; tile < ntiles; tile += gridDim.x) {
        size_t tile64 = (size_t)tile * 64;
        if (t < 64) {
            sidx[t] = eidx[tile64 + t];
            tidx[t] = eidx[(size_t)E + tile64 + t];
        }
        __syncthreads();

        f32x4 acc[4];
        #pragma unroll
        for (int nt = 0; nt < 4; nt++) acc[nt] = (f32x4){0.f, 0.f, 0.f, 0.f};

        int e16 = w * 16 + (lane & 15);
        #pragma unroll
        for (int kk = 0; kk < 6; kk++) {
            bf16x8 a;
            if (kk < 4) {
                int nd = (kk < 2) ? sidx[e16] : tidx[e16];
                a = *(const bf16x8*)(nnb + (size_t)nd * 64 + (kk & 1) * 32 + (lane >> 4) * 8);
            } else {
                const f32x4* p = (const f32x4*)(ef + (tile64 + (size_t)e16) * 64
                                                + (kk - 4) * 32 + (lane >> 4) * 8);
                f32x4 x0 = __builtin_nontemporal_load(p);
                f32x4 x1 = __builtin_nontemporal_load(p + 1);
                a[0] = f2bf(x0.x); a[1] = f2bf(x0.y); a[2] = f2bf(x0.z); a[3] = f2bf(x0.w);
                a[4] = f2bf(x1.x); a[5] = f2bf(x1.y); a[6] = f2bf(x1.z); a[7] = f2bf(x1.w);
            }
            #pragma unroll
            for (int nt = 0; nt < 4; nt++) {
                int n = nt * 16 + (lane & 15);
                int kby = kk * 64 + (lane >> 4) * 16;
                bf16x8 b = *(const bf16x8*)((const char*)sWt1 + n * 384 + swz(n, kby));
                acc[nt] = __builtin_amdgcn_mfma_f32_16x16x32_bf16(a, b, acc[nt], 0, 0, 0);
            }
        }

        // bias + exact GELU + second layer [64,64]@[64,2] via in-register shfl reduce.
        #pragma unroll
        for (int r = 0; r < 4; r++) {
            float p0 = 0.f, p1 = 0.f;
            #pragma unroll
            for (int nt = 0; nt < 4; nt++) {
                int col = nt * 16 + (lane & 15);
                float h = acc[nt][r] + sb1[col];
                float g = 0.5f * h * (1.f + erff(h * 0.70710678118654752f));
                p0 += g * sW2[col * 2 + 0];
                p1 += g * sW2[col * 2 + 1];
            }
            #pragma unroll
            for (int o = 1; o < 16; o <<= 1) {
                p0 += __shfl_xor(p0, o, 64);
                p1 += __shfl_xor(p1, o, 64);
            }
            if ((lane & 15) == 0) {
                int row = w * 16 + (lane >> 4) * 4 + r;
                out[(tile64 + (size_t)row) * 2 + 0] = p0 + sb2[0];
                out[(tile64 + (size_t)row) * 2 + 1] = p1 + sb2[1];
            }
        }
        __syncthreads();
    }
}

extern "C" void kernel_launch(void* const* d_in, const int* in_sizes, int n_in,
                              void* d_out, int out_size, void* d_ws, size_t ws_size,
                              hipStream_t stream)
{
    const float* node = (const float*)d_in[0];
    const float* ef   = (const float*)d_in[1];
    const int*   eidx = (const int*)d_in[2];
    const float* Wq   = (const float*)d_in[3];
    const float* Wk   = (const float*)d_in[4];
    const float* Wv   = (const float*)d_in[5];
    const float* We   = (const float*)d_in[6];
    const float* Wo   = (const float*)d_in[7];
    const float* W1   = (const float*)d_in[8];
    const float* b1   = (const float*)d_in[9];
    const float* W2   = (const float*)d_in[10];
    const float* b2   = (const float*)d_in[11];
    float* out = (float*)d_out;

    int N = in_sizes[0] / 64;
    int E = in_sizes[1] / 64;
    size_t N64 = (size_t)N * 64;
    int NB = (N + 255) / 256;

    // workspace layout (16B-aligned first)
    int4*  sortedq = (int4*)d_ws;                    // E
    short* qb   = (short*)(sortedq + E);             // N64
    short* kb_  = qb + N64;
    short* vb   = kb_ + N64;
    short* nnb  = vb + N64;
    float* agg  = (float*)(nnb + N64);               // N*64, zeroed
    float* denom = agg + N64;                        // N*4, zeroed
    int*   cnt   = (int*)(denom + (size_t)N * 4);    // N, zeroed
    int*   cursor = cnt + N;                         // N
    int*   tmp    = cursor + N;                      // N
    int*   bsum   = tmp + N;                         // 256
    int*   boff   = bsum + 256;                      // 256

    // zero agg + denom + cnt in one contiguous memset
    hipMemsetAsync(agg, 0, (N64 + (size_t)N * 4 + (size_t)N) * 4, stream);

    hist_kernel<<<2048, 256, 0, stream>>>(eidx, cnt, E);
    scanA_kernel<<<NB, 256, 0, stream>>>(cnt, tmp, bsum, N);
    scanB_kernel<<<1, 256, 0, stream>>>(bsum, boff, NB);
    scanC_kernel<<<NB, 256, 0, stream>>>(cnt, tmp, boff, cursor, N);
    scatter_kernel<<<2048, 256, 0, stream>>>(eidx, cursor, sortedq, E);
    qkv_kernel<<<(N + 63) / 64, 256, 0, stream>>>(node, Wq, Wk, Wv, qb, kb_, vb, N);
    edge_kernel<<<2048, 256, 0, stream>>>(ef, sortedq, qb, kb_, vb, We, denom, agg, E);
    wo_kernel<<<(N + 63) / 64, 256, 0, stream>>>(agg, denom, node, Wo, nnb, N);
    cls_kernel<<<2048, 256, 0, stream>>>(nnb, ef, eidx, W1, b1, W2, b2, out, E);
}